// Round 7
// baseline (156.095 us; speedup 1.0000x reference)
//
#include <hip/hip_runtime.h>
#include <stdint.h>

// Problem constants
#define SEQ   2048
#define EMB   1024
#define PROJ  1024
#define HEADS 16
#define HD    64
#define BATCH 2
#define MROWS (BATCH * SEQ)   // 4096
#define QKVN  3072            // fused QKV output width

typedef __attribute__((ext_vector_type(8))) __bf16 bf16x8;
typedef __attribute__((ext_vector_type(4))) __bf16 bf16x4;
typedef __attribute__((ext_vector_type(4))) float  f32x4;

static __device__ __forceinline__ __bf16 f2b(float f) {
  union { float f; uint32_t u; } a; a.f = f;
  uint32_t r = a.u + 0x7FFFu + ((a.u >> 16) & 1u);
  union { uint16_t u; __bf16 b; } o; o.u = (uint16_t)(r >> 16);
  return o.b;
}

#define GLOAD_LDS16(gsrc, ldst)                                                \
  __builtin_amdgcn_global_load_lds(                                            \
      (const __attribute__((address_space(1))) void*)(gsrc),                   \
      (__attribute__((address_space(3))) void*)(ldst), 16, 0, 0)

// ---------------------------------------------------------------------------
// fp32 -> bf16 elementwise cast (vectorized 4/thread)
// ---------------------------------------------------------------------------
__global__ void cast_f32_bf16(const float* __restrict__ in,
                              __bf16* __restrict__ out, int n) {
  int i = (blockIdx.x * blockDim.x + threadIdx.x) * 4;
  if (i + 3 < n) {
    float4 v = *reinterpret_cast<const float4*>(in + i);
    bf16x4 o;
    o[0] = f2b(v.x); o[1] = f2b(v.y); o[2] = f2b(v.z); o[3] = f2b(v.w);
    *reinterpret_cast<bf16x4*>(out + i) = o;
  }
}

// ---------------------------------------------------------------------------
// Transpose + cast the 4 weight matrices. z=0..2 -> rows z*1024.. of WqkvT,
// z=3 -> WoT. T[n][k] = (bf16) W[k][n].
// ---------------------------------------------------------------------------
__global__ void transpose_cast(const float* __restrict__ W0, const float* __restrict__ W1,
                               const float* __restrict__ W2, const float* __restrict__ W3,
                               __bf16* __restrict__ Tqkv, __bf16* __restrict__ To) {
  const float* W; __bf16* T;
  switch (blockIdx.z) {
    case 0: W = W0; T = Tqkv;                       break;
    case 1: W = W1; T = Tqkv + (size_t)1024 * 1024; break;
    case 2: W = W2; T = Tqkv + (size_t)2048 * 1024; break;
    default: W = W3; T = To;                        break;
  }
  __shared__ float tile[32][33];
  int k0 = blockIdx.x * 32, n0 = blockIdx.y * 32;
  int tx = threadIdx.x & 31, ty = threadIdx.x >> 5;  // 256 thr: ty 0..7
#pragma unroll
  for (int r = ty; r < 32; r += 8)
    tile[r][tx] = W[(size_t)(k0 + r) * 1024 + n0 + tx];
  __syncthreads();
#pragma unroll
  for (int r = ty; r < 32; r += 8)
    T[(size_t)(n0 + r) * 1024 + k0 + tx] = f2b(tile[tx][r]);
}

// ---------------------------------------------------------------------------
// bf16 GEMM, C = A[M,K] * Bt^T (Bt[N][K]). Tile BM x 128, BK=32.
// 256 thr = 4 waves in 2x2; wave tile (BM/2) x 64. MFMA 16x16x32.
// SCALE_Q: multiply output by 0.125 when col < 1024 (attention Q pre-scale).
// ---------------------------------------------------------------------------
template <int BM, bool OUT_BF16, bool SCALE_Q>
__global__ __launch_bounds__(256) void gemm_bt(const __bf16* __restrict__ A,
                                               const __bf16* __restrict__ Bt,
                                               void* __restrict__ Cout,
                                               int M, int N, int K) {
  constexpr int MI = BM / 32;  // m-frags per wave
  __shared__ __align__(16) __bf16 As[BM * 32];
  __shared__ __align__(16) __bf16 Bs[128 * 32];
  const int t = threadIdx.x;
  const int lane = t & 63, w = t >> 6;
  const int g = lane >> 4, l15 = lane & 15;
  const int m0 = blockIdx.x * BM, n0 = blockIdx.y * 128;
  const int wr = w >> 1, wc = w & 1;

  f32x4 acc[MI][4];
#pragma unroll
  for (int i = 0; i < MI; i++)
#pragma unroll
    for (int j = 0; j < 4; j++) acc[i][j] = {0.f, 0.f, 0.f, 0.f};

  for (int k0 = 0; k0 < K; k0 += 32) {
    __syncthreads();
#pragma unroll
    for (int c = t; c < BM * 4; c += 256)  // A tile [BM][32]
      GLOAD_LDS16(A + (size_t)(m0 + (c >> 2)) * K + k0 + (c & 3) * 8, As + c * 8);
#pragma unroll
    for (int c = t; c < 512; c += 256)     // Bt tile [128][32]
      GLOAD_LDS16(Bt + (size_t)(n0 + (c >> 2)) * K + k0 + (c & 3) * 8, Bs + c * 8);
    __syncthreads();

    bf16x8 af[MI], bfr[4];
#pragma unroll
    for (int mi = 0; mi < MI; mi++)
      af[mi] = *reinterpret_cast<const bf16x8*>(As + (wr * (BM / 2) + mi * 16 + l15) * 32 + g * 8);
#pragma unroll
    for (int ni = 0; ni < 4; ni++)
      bfr[ni] = *reinterpret_cast<const bf16x8*>(Bs + (wc * 64 + ni * 16 + l15) * 32 + g * 8);
#pragma unroll
    for (int mi = 0; mi < MI; mi++)
#pragma unroll
      for (int ni = 0; ni < 4; ni++)
        acc[mi][ni] = __builtin_amdgcn_mfma_f32_16x16x32_bf16(af[mi], bfr[ni], acc[mi][ni], 0, 0, 0);
  }

#pragma unroll
  for (int mi = 0; mi < MI; mi++)
#pragma unroll
    for (int ni = 0; ni < 4; ni++) {
      int row = m0 + wr * (BM / 2) + mi * 16 + g * 4;
      int col = n0 + wc * 64 + ni * 16 + l15;
#pragma unroll
      for (int r = 0; r < 4; r++) {
        float v = acc[mi][ni][r];
        if (SCALE_Q && col < 1024) v *= 0.125f;
        if (OUT_BF16)
          ((__bf16*)Cout)[(size_t)(row + r) * N + col] = f2b(v);
        else
          ((float*)Cout)[(size_t)(row + r) * N + col] = v;
      }
    }
}

// ---------------------------------------------------------------------------
// V pre-transpose: Vt[(bh*64 + d)*2048 + s] = QKV[b][s][2048 + h*64 + d].
// ---------------------------------------------------------------------------
__global__ void v_transpose(const __bf16* __restrict__ QKV, __bf16* __restrict__ Vt) {
  const int sb = blockIdx.x, bh = blockIdx.y;
  const int lane = threadIdx.x & 63, w = threadIdx.x >> 6;
  const int b = bh >> 4, h = bh & 15;
  const int s = sb * 64 + lane;
  const __bf16* src = QKV + (size_t)b * SEQ * QKVN + (size_t)s * QKVN + 2048 + h * 64 + w * 16;
  bf16x8 v0 = *reinterpret_cast<const bf16x8*>(src);
  bf16x8 v1 = *reinterpret_cast<const bf16x8*>(src + 8);
  __bf16* dst = Vt + ((size_t)bh * 64 + w * 16) * 2048 + s;
#pragma unroll
  for (int j = 0; j < 8; j++) dst[(size_t)j * 2048] = v0[j];
#pragma unroll
  for (int j = 0; j < 8; j++) dst[(size_t)(8 + j) * 2048] = v1[j];
}

// ---------------------------------------------------------------------------
// One KV-tile-range piece of a chunk (32 q-rows). r6's verified inner loop.
// Tiles [a, b) of chunk with Tc total tiles; diag mask iff it == Tc-1.
// ---------------------------------------------------------------------------
__device__ __forceinline__ void kv_piece(const __bf16* __restrict__ Qg,
                                         const __bf16* __restrict__ Kg,
                                         const __bf16* __restrict__ VtH,
                                         int qw, int a, int b, int Tc, int lane,
                                         __bf16 (*Pw)[72],
                                         f32x4 (&acco)[2][4], float (&mrun)[2],
                                         float (&lrun)[2]) {
  const int g = lane >> 4, l15 = lane & 15;

  // Q fragments: qf[m][ks][j] = Q[qw+m*16+l15][ks*32+g*8+j]
  bf16x8 qf[2][2];
#pragma unroll
  for (int m = 0; m < 2; m++)
#pragma unroll
    for (int ks = 0; ks < 2; ks++)
      qf[m][ks] = *reinterpret_cast<const bf16x8*>(
          Qg + (size_t)(qw + m * 16 + l15) * QKVN + ks * 32 + g * 8);

  // preload K fragments for first tile
  bf16x8 kf[4][2], kn[4][2];
#pragma unroll
  for (int nb = 0; nb < 4; nb++) {
    const __bf16* kr = Kg + (size_t)(a * 64 + nb * 16 + l15) * QKVN + g * 8;
    kf[nb][0] = *reinterpret_cast<const bf16x8*>(kr);
    kf[nb][1] = *reinterpret_cast<const bf16x8*>(kr + 32);
  }

  for (int it = a; it < b; ++it) {
    const int kv0 = it * 64;
    const bool diag = (it == Tc - 1);

    // V fragments for current tile
    bf16x8 vb[4][2];
#pragma unroll
    for (int nd = 0; nd < 4; nd++)
#pragma unroll
      for (int ks = 0; ks < 2; ks++)
        vb[nd][ks] = *reinterpret_cast<const bf16x8*>(
            VtH + (size_t)(nd * 16 + l15) * 2048 + kv0 + ks * 32 + g * 8);

    // prefetch next tile's K fragments
    if (it + 1 < b) {
#pragma unroll
      for (int nb = 0; nb < 4; nb++) {
        const __bf16* kr = Kg + (size_t)(kv0 + 64 + nb * 16 + l15) * QKVN + g * 8;
        kn[nb][0] = *reinterpret_cast<const bf16x8*>(kr);
        kn[nb][1] = *reinterpret_cast<const bf16x8*>(kr + 32);
      }
    }

    // ---- QK^T (swapped): accS[nb][m], D[kv][q]
    f32x4 accS[4][2];
#pragma unroll
    for (int nb = 0; nb < 4; nb++)
#pragma unroll
      for (int m = 0; m < 2; m++) accS[nb][m] = {0.f, 0.f, 0.f, 0.f};
#pragma unroll
    for (int nb = 0; nb < 4; nb++)
#pragma unroll
      for (int m = 0; m < 2; m++) {
        accS[nb][m] = __builtin_amdgcn_mfma_f32_16x16x32_bf16(kf[nb][0], qf[m][0], accS[nb][m], 0, 0, 0);
        accS[nb][m] = __builtin_amdgcn_mfma_f32_16x16x32_bf16(kf[nb][1], qf[m][1], accS[nb][m], 0, 0, 0);
      }

    // ---- causal mask (diagonal tile only)
    if (diag) {
#pragma unroll
      for (int nb = 0; nb < 4; nb++)
#pragma unroll
        for (int m = 0; m < 2; m++)
#pragma unroll
          for (int r = 0; r < 4; r++) {
            int kvi = kv0 + nb * 16 + g * 4 + r;
            int qi = qw + m * 16 + l15;
            if (kvi > qi) accS[nb][m][r] = -1e30f;
          }
    }

    // ---- online softmax (row = lane's own q = m*16+l15), defer-max THR=8
#pragma unroll
    for (int m = 0; m < 2; m++) {
      float pmax = -1e30f;
#pragma unroll
      for (int nb = 0; nb < 4; nb++)
#pragma unroll
        for (int r = 0; r < 4; r++) pmax = fmaxf(pmax, accS[nb][m][r]);
      pmax = fmaxf(pmax, __shfl_xor(pmax, 16));
      pmax = fmaxf(pmax, __shfl_xor(pmax, 32));
      if (!__all(pmax <= mrun[m] + 8.0f)) {
        float mnew = fmaxf(mrun[m], pmax);
        float corr = __expf(mrun[m] - mnew);
        mrun[m] = mnew;
        lrun[m] *= corr;
#pragma unroll
        for (int r = 0; r < 4; r++) {
          float cr = __shfl(corr, (g << 4) + (g << 2) + r);
#pragma unroll
          for (int nd = 0; nd < 4; nd++) acco[m][nd][r] *= cr;
        }
      }
      float lsum = 0.f;
#pragma unroll
      for (int nb = 0; nb < 4; nb++) {
        bf16x4 pk;
#pragma unroll
        for (int r = 0; r < 4; r++) {
          float pv = __expf(accS[nb][m][r] - mrun[m]);
          lsum += pv;
          pk[r] = (__bf16)pv;
        }
        *reinterpret_cast<bf16x4*>(&Pw[m * 16 + l15][nb * 16 + g * 4]) = pk;
      }
      lsum += __shfl_xor(lsum, 16);
      lsum += __shfl_xor(lsum, 32);
      lrun[m] += lsum;
    }

    // ---- PV: O[q][d] += P[q][kv] * V[kv][d]
#pragma unroll
    for (int m = 0; m < 2; m++) {
      bf16x8 pa0 = *reinterpret_cast<const bf16x8*>(&Pw[m * 16 + l15][g * 8]);
      bf16x8 pa1 = *reinterpret_cast<const bf16x8*>(&Pw[m * 16 + l15][32 + g * 8]);
#pragma unroll
      for (int nd = 0; nd < 4; nd++) {
        acco[m][nd] = __builtin_amdgcn_mfma_f32_16x16x32_bf16(pa0, vb[nd][0], acco[m][nd], 0, 0, 0);
        acco[m][nd] = __builtin_amdgcn_mfma_f32_16x16x32_bf16(pa1, vb[nd][1], acco[m][nd], 0, 0, 0);
      }
    }

    if (it + 1 < b) {
#pragma unroll
      for (int nb = 0; nb < 4; nb++) {
        kf[nb][0] = kn[nb][0];
        kf[nb][1] = kn[nb][1];
      }
    }
  }
}

// store normalized partial (O/l fp16 rows [32][72]) + (m,l) per row
__device__ __forceinline__ void store_partial(_Float16* dst, float (*ml)[2],
                                              f32x4 (&acco)[2][4], float (&mrun)[2],
                                              float (&lrun)[2], int lane) {
  const int g = lane >> 4, l15 = lane & 15;
#pragma unroll
  for (int m = 0; m < 2; m++) {
    float inv = lrun[m] > 0.f ? 1.0f / lrun[m] : 0.f;
    if (g == 0) { ml[m * 16 + l15][0] = mrun[m]; ml[m * 16 + l15][1] = lrun[m]; }
#pragma unroll
    for (int r = 0; r < 4; r++) {
      float ir = __shfl(inv, (g << 4) + (g << 2) + r);
#pragma unroll
      for (int nd = 0; nd < 4; nd++)
        dst[(m * 16 + g * 4 + r) * 72 + nd * 16 + l15] = (_Float16)(acco[m][nd][r] * ir);
    }
  }
}

// ---------------------------------------------------------------------------
// Causal flash attention, balanced split-KV. Grid 1024 blocks x 256 thr
// (4 waves) = exactly 4 blocks/CU resident, 16 waves/CU, one generation.
// Block = pair {p, 63-p} = 33 KV-units over the concat [heavy(Th) | light(Tl)]
// list; wave w owns units [33w/4, 33(w+1)/4) = 8,8,8,9 -> every wave in the
// grid has ~equal serial work (r3-r6 invariant: 33 units/SIMD; makespan was
// set by the heaviest wave). A wave spans <=2 chunks: partials (O/l fp16 +
// m,l) -> LDS; wave0 flash-combines heavy chunk, wave3 light chunk.
// NOTE launch_bounds min-waves stays 2: forcing 4 caps VGPR at 64 and spills
// (round-5: WRITE_SIZE 15->317MB). Natural alloc ~108 VGPR -> 4 waves/SIMD.
// ---------------------------------------------------------------------------
__global__ __launch_bounds__(256, 2) void attn_fwd(const __bf16* __restrict__ QKV,
                                                   const __bf16* __restrict__ Vt,
                                                   __bf16* __restrict__ ctx) {
  const int id = blockIdx.x;
  const int bh = (id & 7) * 4 + ((id >> 3) & 3);
  const int p  = id >> 5;                       // 0..31
  const int b = bh >> 4, h = bh & 15;
  const int t = threadIdx.x, lane = t & 63, w = t >> 6;  // w 0..3
  const int g = lane >> 4, l15 = lane & 15;

  const int ch_h = 63 - p, ch_l = p;
  const int Th = ch_h / 2 + 1;                  // 17..32
  const int Tl = ch_l / 2 + 1;                  // 33 - Th
  const int u0 = (33 * w) >> 2;                 // 0,8,16,24
  const int u1 = (33 * (w + 1)) >> 2;           // 8,16,24,33

  __shared__ __align__(16) __bf16 P_lds[4][32][72];      // P staging / final partial
  __shared__ __align__(16) _Float16 early[2][32][72];    // split wave's h partial
  __shared__ float mlbuf[4][2][32][2];                   // [wave][piece h/l][row][m,l]

  const __bf16* Qg  = QKV + (size_t)b * SEQ * QKVN + h * 64;
  const __bf16* Kg  = QKV + (size_t)b * SEQ * QKVN + 1024 + h * 64;
  const __bf16* VtH = Vt + (size_t)bh * 64 * 2048;

  const int hb = (u1 < Th) ? u1 : Th;           // h piece = [u0, hb)
  const bool hasH = u0 < hb;
  const bool hasL = u1 > Th;

  f32x4 acco[2][4];
  float mrun[2], lrun[2];

  if (hasH) {
#pragma unroll
    for (int m = 0; m < 2; m++) {
      mrun[m] = -1e30f; lrun[m] = 0.f;
#pragma unroll
      for (int nd = 0; nd < 4; nd++) acco[m][nd] = {0.f, 0.f, 0.f, 0.f};
    }
    kv_piece(Qg, Kg, VtH, ch_h * 32, u0, hb, Th, lane, P_lds[w], acco, mrun, lrun);
    if (hasL) {
      // split wave (w is 2 or 3): h partial -> early slot, then do l piece
      store_partial(&early[w - 2][0][0], mlbuf[w][0], acco, mrun, lrun, lane);
    } else {
      store_partial((_Float16*)&P_lds[w][0][0], mlbuf[w][0], acco, mrun, lrun, lane);
    }
  }
  if (hasL) {
    const int a2 = (u0 > Th ? u0 : Th) - Th;
    const int b2 = u1 - Th;
#pragma unroll
    for (int m = 0; m < 2; m++) {
      mrun[m] = -1e30f; lrun[m] = 0.f;
#pragma unroll
      for (int nd = 0; nd < 4; nd++) acco[m][nd] = {0.f, 0.f, 0.f, 0.f};
    }
    kv_piece(Qg, Kg, VtH, ch_l * 32, a2, b2, Tl, lane, P_lds[w], acco, mrun, lrun);
    store_partial((_Float16*)&P_lds[w][0][0], mlbuf[w][1], acco, mrun, lrun, lane);
  }

  __syncthreads();

  // ---------------- merge (wave 0: heavy chunk; wave 3: light chunk) -------
  if (w == 0 || w == 3) {
    const bool mh = (w == 0);
    const int chunk = mh ? ch_h : ch_l;
    __bf16* Cg = ctx + (size_t)b * SEQ * 1024 + h * 64 + (size_t)chunk * 32 * 1024;

    // contributor k valid + source select (all wave-uniform)
    bool val[4]; const _Float16* src[4]; const float (*mlp[4])[2];
#pragma unroll
    for (int k = 0; k < 4; k++) {
      int ku0 = (33 * k) >> 2, ku1 = (33 * (k + 1)) >> 2;
      if (mh) {
        val[k] = ku0 < Th;
        bool splitk = (ku0 < Th) && (ku1 > Th);
        int sl = (k >= 2) ? k - 2 : 0;
        src[k] = splitk ? &early[sl][0][0] : (const _Float16*)&P_lds[k][0][0];
        mlp[k] = mlbuf[k][0];
      } else {
        val[k] = ku1 > Th;
        src[k] = (const _Float16*)&P_lds[k][0][0];
        mlp[k] = mlbuf[k][1];
      }
    }

#pragma unroll
    for (int m = 0; m < 2; m++)
#pragma unroll
      for (int r = 0; r < 4; r++) {
        const int row = m * 16 + g * 4 + r;
        float mx = -1e30f;
#pragma unroll
        for (int k = 0; k < 4; k++)
          if (val[k]) mx = fmaxf(mx, mlp[k][row][0]);
        float a[4], asum = 0.f;
#pragma unroll
        for (int k = 0; k < 4; k++) {
          a[k] = 0.f;
          if (val[k]) { a[k] = mlp[k][row][1] * __expf(mlp[k][row][0] - mx); asum += a[k]; }
        }
        float inv = 1.0f / asum;
#pragma unroll
        for (int nd = 0; nd < 4; nd++) {
          float o = 0.f;
#pragma unroll
          for (int k = 0; k < 4; k++)
            if (val[k]) o += a[k] * (float)src[k][row * 72 + nd * 16 + l15];
          Cg[(size_t)row * 1024 + nd * 16 + l15] = (__bf16)(o * inv);
        }
      }
  }
}

// ---------------------------------------------------------------------------
extern "C" void kernel_launch(void* const* d_in, const int* in_sizes, int n_in,
                              void* d_out, int out_size, void* d_ws, size_t ws_size,
                              hipStream_t stream) {
  const float* X  = (const float*)d_in[0];
  const float* Wq = (const float*)d_in[1];
  const float* Wk = (const float*)d_in[2];
  const float* Wv = (const float*)d_in[3];
  const float* Wo = (const float*)d_in[4];
  float* out = (float*)d_out;

  uint8_t* ws = (uint8_t*)d_ws;
  size_t off = 0;
  const size_t actBytes = (size_t)MROWS * 1024 * 2;          // 8 MB
  __bf16* Xb    = (__bf16*)(ws + off); off += actBytes;      // freed after QKV gemm
  __bf16* WqkvT = (__bf16*)(ws + off); off += (size_t)QKVN * 1024 * 2;
  __bf16* WoT   = (__bf16*)(ws + off); off += (size_t)1024 * 1024 * 2;
  __bf16* QKV   = (__bf16*)(ws + off); off += (size_t)MROWS * QKVN * 2;
  __bf16* Vt    = (__bf16*)(ws + off); off += actBytes;
  __bf16* Cb    = Xb;  // alias: X dead after QKV projection

  // 1) casts
  cast_f32_bf16<<<dim3(MROWS * 1024 / 4 / 256), dim3(256), 0, stream>>>(X, Xb, MROWS * 1024);
  transpose_cast<<<dim3(32, 32, 4), dim3(256), 0, stream>>>(Wq, Wk, Wv, Wo, WqkvT, WoT);

  // 2) fused QKV projection (Q pre-scaled by 1/8), 128x128 tiles
  gemm_bt<128, true, true><<<dim3(MROWS / 128, QKVN / 128), dim3(256), 0, stream>>>(
      Xb, WqkvT, QKV, MROWS, QKVN, EMB);

  // 3) V pre-transpose, then causal flash attention (balanced split-KV)
  v_transpose<<<dim3(SEQ / 64, BATCH * HEADS), dim3(256), 0, stream>>>(QKV, Vt);
  attn_fwd<<<dim3(1024), dim3(256), 0, stream>>>(QKV, Vt, Cb);

  // 4) output projection (fp32 out), 64x128 tiles (512 blocks, 2/CU)
  gemm_bt<64, false, false><<<dim3(MROWS / 64, PROJ / 128), dim3(256), 0, stream>>>(
      Cb, WoT, out, MROWS, PROJ, PROJ);
}

// Round 9
// 115.865 us; speedup vs baseline: 1.3472x; 1.3472x over previous
//
#include <hip/hip_runtime.h>
#include <stdint.h>

// Problem constants
#define SEQ   2048
#define EMB   1024
#define PROJ  1024
#define HEADS 16
#define HD    64
#define BATCH 2
#define MROWS (BATCH * SEQ)   // 4096
#define QKVN  3072            // fused QKV output width

typedef __attribute__((ext_vector_type(8))) __bf16 bf16x8;
typedef __attribute__((ext_vector_type(4))) __bf16 bf16x4;
typedef __attribute__((ext_vector_type(4))) float  f32x4;

static __device__ __forceinline__ __bf16 f2b(float f) {
  union { float f; uint32_t u; } a; a.f = f;
  uint32_t r = a.u + 0x7FFFu + ((a.u >> 16) & 1u);
  union { uint16_t u; __bf16 b; } o; o.u = (uint16_t)(r >> 16);
  return o.b;
}

#define GLOAD_LDS16(gsrc, ldst)                                                \
  __builtin_amdgcn_global_load_lds(                                            \
      (const __attribute__((address_space(1))) void*)(gsrc),                   \
      (__attribute__((address_space(3))) void*)(ldst), 16, 0, 0)

// ---------------------------------------------------------------------------
// fp32 -> bf16 elementwise cast (vectorized 4/thread)
// ---------------------------------------------------------------------------
__global__ void cast_f32_bf16(const float* __restrict__ in,
                              __bf16* __restrict__ out, int n) {
  int i = (blockIdx.x * blockDim.x + threadIdx.x) * 4;
  if (i + 3 < n) {
    float4 v = *reinterpret_cast<const float4*>(in + i);
    bf16x4 o;
    o[0] = f2b(v.x); o[1] = f2b(v.y); o[2] = f2b(v.z); o[3] = f2b(v.w);
    *reinterpret_cast<bf16x4*>(out + i) = o;
  }
}

// ---------------------------------------------------------------------------
// Transpose + cast the 4 weight matrices. z=0..2 -> rows z*1024.. of WqkvT,
// z=3 -> WoT. T[n][k] = (bf16) W[k][n].
// ---------------------------------------------------------------------------
__global__ void transpose_cast(const float* __restrict__ W0, const float* __restrict__ W1,
                               const float* __restrict__ W2, const float* __restrict__ W3,
                               __bf16* __restrict__ Tqkv, __bf16* __restrict__ To) {
  const float* W; __bf16* T;
  switch (blockIdx.z) {
    case 0: W = W0; T = Tqkv;                       break;
    case 1: W = W1; T = Tqkv + (size_t)1024 * 1024; break;
    case 2: W = W2; T = Tqkv + (size_t)2048 * 1024; break;
    default: W = W3; T = To;                        break;
  }
  __shared__ float tile[32][33];
  int k0 = blockIdx.x * 32, n0 = blockIdx.y * 32;
  int tx = threadIdx.x & 31, ty = threadIdx.x >> 5;  // 256 thr: ty 0..7
#pragma unroll
  for (int r = ty; r < 32; r += 8)
    tile[r][tx] = W[(size_t)(k0 + r) * 1024 + n0 + tx];
  __syncthreads();
#pragma unroll
  for (int r = ty; r < 32; r += 8)
    T[(size_t)(n0 + r) * 1024 + k0 + tx] = f2b(tile[tx][r]);
}

// ---------------------------------------------------------------------------
// bf16 GEMM, C = A[M,K] * Bt^T (Bt[N][K]). Tile BM x 128, BK=32.
// 256 thr = 4 waves in 2x2; wave tile (BM/2) x 64. MFMA 16x16x32.
// SCALE_Q: multiply output by 0.125 when col < 1024 (attention Q pre-scale).
// ---------------------------------------------------------------------------
template <int BM, bool OUT_BF16, bool SCALE_Q>
__global__ __launch_bounds__(256) void gemm_bt(const __bf16* __restrict__ A,
                                               const __bf16* __restrict__ Bt,
                                               void* __restrict__ Cout,
                                               int M, int N, int K) {
  constexpr int MI = BM / 32;  // m-frags per wave
  __shared__ __align__(16) __bf16 As[BM * 32];
  __shared__ __align__(16) __bf16 Bs[128 * 32];
  const int t = threadIdx.x;
  const int lane = t & 63, w = t >> 6;
  const int g = lane >> 4, l15 = lane & 15;
  const int m0 = blockIdx.x * BM, n0 = blockIdx.y * 128;
  const int wr = w >> 1, wc = w & 1;

  f32x4 acc[MI][4];
#pragma unroll
  for (int i = 0; i < MI; i++)
#pragma unroll
    for (int j = 0; j < 4; j++) acc[i][j] = {0.f, 0.f, 0.f, 0.f};

  for (int k0 = 0; k0 < K; k0 += 32) {
    __syncthreads();
#pragma unroll
    for (int c = t; c < BM * 4; c += 256)  // A tile [BM][32]
      GLOAD_LDS16(A + (size_t)(m0 + (c >> 2)) * K + k0 + (c & 3) * 8, As + c * 8);
#pragma unroll
    for (int c = t; c < 512; c += 256)     // Bt tile [128][32]
      GLOAD_LDS16(Bt + (size_t)(n0 + (c >> 2)) * K + k0 + (c & 3) * 8, Bs + c * 8);
    __syncthreads();

    bf16x8 af[MI], bfr[4];
#pragma unroll
    for (int mi = 0; mi < MI; mi++)
      af[mi] = *reinterpret_cast<const bf16x8*>(As + (wr * (BM / 2) + mi * 16 + l15) * 32 + g * 8);
#pragma unroll
    for (int ni = 0; ni < 4; ni++)
      bfr[ni] = *reinterpret_cast<const bf16x8*>(Bs + (wc * 64 + ni * 16 + l15) * 32 + g * 8);
#pragma unroll
    for (int mi = 0; mi < MI; mi++)
#pragma unroll
      for (int ni = 0; ni < 4; ni++)
        acc[mi][ni] = __builtin_amdgcn_mfma_f32_16x16x32_bf16(af[mi], bfr[ni], acc[mi][ni], 0, 0, 0);
  }

#pragma unroll
  for (int mi = 0; mi < MI; mi++)
#pragma unroll
    for (int ni = 0; ni < 4; ni++) {
      int row = m0 + wr * (BM / 2) + mi * 16 + g * 4;
      int col = n0 + wc * 64 + ni * 16 + l15;
#pragma unroll
      for (int r = 0; r < 4; r++) {
        float v = acc[mi][ni][r];
        if (SCALE_Q && col < 1024) v *= 0.125f;
        if (OUT_BF16)
          ((__bf16*)Cout)[(size_t)(row + r) * N + col] = f2b(v);
        else
          ((float*)Cout)[(size_t)(row + r) * N + col] = v;
      }
    }
}

// ---------------------------------------------------------------------------
// V pre-transpose: Vt[(bh*64 + d)*2048 + s] = QKV[b][s][2048 + h*64 + d].
// ---------------------------------------------------------------------------
__global__ void v_transpose(const __bf16* __restrict__ QKV, __bf16* __restrict__ Vt) {
  const int sb = blockIdx.x, bh = blockIdx.y;
  const int lane = threadIdx.x & 63, w = threadIdx.x >> 6;
  const int b = bh >> 4, h = bh & 15;
  const int s = sb * 64 + lane;
  const __bf16* src = QKV + (size_t)b * SEQ * QKVN + (size_t)s * QKVN + 2048 + h * 64 + w * 16;
  bf16x8 v0 = *reinterpret_cast<const bf16x8*>(src);
  bf16x8 v1 = *reinterpret_cast<const bf16x8*>(src + 8);
  __bf16* dst = Vt + ((size_t)bh * 64 + w * 16) * 2048 + s;
#pragma unroll
  for (int j = 0; j < 8; j++) dst[(size_t)j * 2048] = v0[j];
#pragma unroll
  for (int j = 0; j < 8; j++) dst[(size_t)(8 + j) * 2048] = v1[j];
}

// ---------------------------------------------------------------------------
// Causal flash attention, LDS-shared K/V, pair-balanced blocks.
// Grid 512 blocks x 256 thr (4 waves) = 2 blocks/CU, 8 waves/CU (2/SIMD).
// id&7 = xcd (owns 4 heads); bh = (id&7)*4 + ((id>>3)&3); pair = id>>5 (0..15).
// Block runs two 64-row members sequentially: mi = pair, then 31-pair
// (mi in [0,32); member rows [64*mi, +64) -- IN-BOUNDS, r8 bug was 128-row
// members indexed to 32). Member mi needs Tm = mi+1 KV tiles; block total =
// (pair+1) + (32-pair) = 33 iters, uniform across ALL blocks.
// Wave w owns 16 rows qw = 64*mi + 16*w to COMPLETION; Tw == Tm for every
// wave (qw+15 < 64*(mi+1)), so no early-exit and diag mask only at it==Tm-1.
// Per iter: K[64][64] + V^T[64][64] staged into double-buffered LDS by all
// 256 threads (reg-staged, XOR-swizzle chunk^=(row&7): 2 lanes/bank = free;
// global loads issued BEFORE compute, ds_writes after = T14 split).
// Swapped QK^T (D[kv][q], lane-local softmax state, M=1), Q pre-scaled 1/8.
// ---------------------------------------------------------------------------
__global__ __launch_bounds__(256, 2) void attn_fwd(const __bf16* __restrict__ QKV,
                                                   const __bf16* __restrict__ Vt,
                                                   __bf16* __restrict__ ctx) {
  const int id = blockIdx.x;
  const int bh = (id & 7) * 4 + ((id >> 3) & 3);
  const int pair = id >> 5;                     // 0..15
  const int b = bh >> 4, h = bh & 15;
  const int tid = threadIdx.x, lane = tid & 63, w = tid >> 6;
  const int g = lane >> 4, l15 = lane & 15;

  __shared__ __align__(16) __bf16 Ks[2][64 * 64];
  __shared__ __align__(16) __bf16 Vs[2][64 * 64];
  __shared__ __align__(16) __bf16 P_lds[4][16][72];

  const __bf16* Qg  = QKV + (size_t)b * SEQ * QKVN + h * 64;
  const __bf16* Kg  = Qg + 1024;
  const __bf16* VtH = Vt + (size_t)bh * 64 * 2048;
  __bf16* Cg = ctx + (size_t)b * SEQ * 1024 + h * 64;

  // staging geometry: 512 16B-chunks per tile; thread handles chunks
  // (r0,j0) and (r1,j0), r1 = r0+32. Swizzled LDS elem offset:
  // row*64 + (j ^ (row&7))*8.
  const int r0 = tid >> 3, j0 = tid & 7;
  const int r1 = r0 + 32;
  const int ls0 = r0 * 64 + ((j0 ^ (r0 & 7)) * 8);
  const int ls1 = r1 * 64 + ((j0 ^ (r1 & 7)) * 8);
  const size_t gk0 = (size_t)r0 * QKVN + j0 * 8;
  const size_t gk1 = (size_t)r1 * QKVN + j0 * 8;
  const size_t gv0 = (size_t)r0 * 2048 + j0 * 8;
  const size_t gv1 = (size_t)r1 * 2048 + j0 * 8;
  const int xw = l15 & 7;  // read-side row XOR ((nb*16+l15)&7 == l15&7)

  for (int mem = 0; mem < 2; ++mem) {
    const int mi = mem ? (31 - pair) : pair;    // 0..31, 64-row members
    const int qw = mi * 64 + 16 * w;            // wave's 16 rows
    const int Tm = mi + 1;

    // Q fragments: qf[ks][j] = Q[qw+l15][ks*32+g*8+j]
    bf16x8 qf[2];
#pragma unroll
    for (int ks = 0; ks < 2; ks++)
      qf[ks] = *reinterpret_cast<const bf16x8*>(
          Qg + (size_t)(qw + l15) * QKVN + ks * 32 + g * 8);

    f32x4 acco[4];
    float mrun = -1e30f, lrun = 0.f;
#pragma unroll
    for (int nd = 0; nd < 4; nd++) acco[nd] = {0.f, 0.f, 0.f, 0.f};

    // prologue: stage tile 0 into buffer 0
    {
      bf16x8 ka = *reinterpret_cast<const bf16x8*>(Kg + gk0);
      bf16x8 kb = *reinterpret_cast<const bf16x8*>(Kg + gk1);
      bf16x8 va = *reinterpret_cast<const bf16x8*>(VtH + gv0);
      bf16x8 vc = *reinterpret_cast<const bf16x8*>(VtH + gv1);
      *reinterpret_cast<bf16x8*>(Ks[0] + ls0) = ka;
      *reinterpret_cast<bf16x8*>(Ks[0] + ls1) = kb;
      *reinterpret_cast<bf16x8*>(Vs[0] + ls0) = va;
      *reinterpret_cast<bf16x8*>(Vs[0] + ls1) = vc;
    }
    __syncthreads();

    for (int it = 0; it < Tm; ++it) {
      const int cur = it & 1, nxt = cur ^ 1;
      const bool hn = (it + 1 < Tm);
      bf16x8 ka, kb, va, vc;
      if (hn) {  // issue next tile's loads early (T14 split)
        const size_t kvn = (size_t)(it + 1) * 64;
        ka = *reinterpret_cast<const bf16x8*>(Kg + kvn * QKVN + gk0);
        kb = *reinterpret_cast<const bf16x8*>(Kg + kvn * QKVN + gk1);
        va = *reinterpret_cast<const bf16x8*>(VtH + kvn + gv0);
        vc = *reinterpret_cast<const bf16x8*>(VtH + kvn + gv1);
      }

      {
        const int kv0 = it * 64;
        const bool diag = (it == Tm - 1);
        const __bf16* Kc = Ks[cur];
        const __bf16* Vc = Vs[cur];

        // fragments from LDS (swizzled)
        bf16x8 kf[4][2], vb[4][2];
#pragma unroll
        for (int nb = 0; nb < 4; nb++) {
          const int row = (nb * 16 + l15) * 64;
#pragma unroll
          for (int ks = 0; ks < 2; ks++) {
            const int co = ((ks * 4 + g) ^ xw) * 8;
            kf[nb][ks] = *reinterpret_cast<const bf16x8*>(Kc + row + co);
            vb[nb][ks] = *reinterpret_cast<const bf16x8*>(Vc + row + co);
          }
        }

        // ---- QK^T (swapped): accS[nb], D[kv][q], q = qw+l15
        f32x4 accS[4];
#pragma unroll
        for (int nb = 0; nb < 4; nb++) accS[nb] = {0.f, 0.f, 0.f, 0.f};
#pragma unroll
        for (int nb = 0; nb < 4; nb++) {
          accS[nb] = __builtin_amdgcn_mfma_f32_16x16x32_bf16(kf[nb][0], qf[0], accS[nb], 0, 0, 0);
          accS[nb] = __builtin_amdgcn_mfma_f32_16x16x32_bf16(kf[nb][1], qf[1], accS[nb], 0, 0, 0);
        }

        // ---- causal mask (diagonal tile only)
        if (diag) {
          const int qi = qw + l15;
#pragma unroll
          for (int nb = 0; nb < 4; nb++)
#pragma unroll
            for (int r = 0; r < 4; r++) {
              int kvi = kv0 + nb * 16 + g * 4 + r;
              if (kvi > qi) accS[nb][r] = -1e30f;
            }
        }

        // ---- online softmax (row = lane's own q = qw+l15), defer-max THR=8
        {
          float pmax = -1e30f;
#pragma unroll
          for (int nb = 0; nb < 4; nb++)
#pragma unroll
            for (int r = 0; r < 4; r++) pmax = fmaxf(pmax, accS[nb][r]);
          pmax = fmaxf(pmax, __shfl_xor(pmax, 16));
          pmax = fmaxf(pmax, __shfl_xor(pmax, 32));
          if (!__all(pmax <= mrun + 8.0f)) {
            float mnew = fmaxf(mrun, pmax);
            float corr = __expf(mrun - mnew);
            mrun = mnew;
            lrun *= corr;
#pragma unroll
            for (int r = 0; r < 4; r++) {
              float cr = __shfl(corr, (g << 4) + (g << 2) + r);
#pragma unroll
              for (int nd = 0; nd < 4; nd++) acco[nd][r] *= cr;
            }
          }
          float lsum = 0.f;
#pragma unroll
          for (int nb = 0; nb < 4; nb++) {
            bf16x4 pk;
#pragma unroll
            for (int r = 0; r < 4; r++) {
              float pv = __expf(accS[nb][r] - mrun);
              lsum += pv;
              pk[r] = (__bf16)pv;
            }
            *reinterpret_cast<bf16x4*>(&P_lds[w][l15][nb * 16 + g * 4]) = pk;
          }
          lsum += __shfl_xor(lsum, 16);
          lsum += __shfl_xor(lsum, 32);
          lrun += lsum;
        }

        // ---- PV: O[q][d] += P[q][kv] * V[kv][d]
        {
          bf16x8 pa0 = *reinterpret_cast<const bf16x8*>(&P_lds[w][l15][g * 8]);
          bf16x8 pa1 = *reinterpret_cast<const bf16x8*>(&P_lds[w][l15][32 + g * 8]);
#pragma unroll
          for (int nd = 0; nd < 4; nd++) {
            acco[nd] = __builtin_amdgcn_mfma_f32_16x16x32_bf16(pa0, vb[nd][0], acco[nd], 0, 0, 0);
            acco[nd] = __builtin_amdgcn_mfma_f32_16x16x32_bf16(pa1, vb[nd][1], acco[nd], 0, 0, 0);
          }
        }
      }

      if (hn) {  // write staged regs to the other buffer
        *reinterpret_cast<bf16x8*>(Ks[nxt] + ls0) = ka;
        *reinterpret_cast<bf16x8*>(Ks[nxt] + ls1) = kb;
        *reinterpret_cast<bf16x8*>(Vs[nxt] + ls0) = va;
        *reinterpret_cast<bf16x8*>(Vs[nxt] + ls1) = vc;
      }
      __syncthreads();
    }

    // epilogue: ctx = O / l for this wave's 16 rows
    {
      float inv = 1.0f / lrun;
#pragma unroll
      for (int r = 0; r < 4; r++) {
        float ir = __shfl(inv, (g << 4) + (g << 2) + r);
        int qrow = qw + g * 4 + r;
#pragma unroll
        for (int nd = 0; nd < 4; nd++)
          Cg[(size_t)qrow * 1024 + nd * 16 + l15] = (__bf16)(acco[nd][r] * ir);
      }
    }
  }
}

// ---------------------------------------------------------------------------
extern "C" void kernel_launch(void* const* d_in, const int* in_sizes, int n_in,
                              void* d_out, int out_size, void* d_ws, size_t ws_size,
                              hipStream_t stream) {
  const float* X  = (const float*)d_in[0];
  const float* Wq = (const float*)d_in[1];
  const float* Wk = (const float*)d_in[2];
  const float* Wv = (const float*)d_in[3];
  const float* Wo = (const float*)d_in[4];
  float* out = (float*)d_out;

  uint8_t* ws = (uint8_t*)d_ws;
  size_t off = 0;
  const size_t actBytes = (size_t)MROWS * 1024 * 2;          // 8 MB
  __bf16* Xb    = (__bf16*)(ws + off); off += actBytes;      // freed after QKV gemm
  __bf16* WqkvT = (__bf16*)(ws + off); off += (size_t)QKVN * 1024 * 2;
  __bf16* WoT   = (__bf16*)(ws + off); off += (size_t)1024 * 1024 * 2;
  __bf16* QKV   = (__bf16*)(ws + off); off += (size_t)MROWS * QKVN * 2;
  __bf16* Vt    = (__bf16*)(ws + off); off += actBytes;
  __bf16* Cb    = Xb;  // alias: X dead after QKV projection

  // 1) casts
  cast_f32_bf16<<<dim3(MROWS * 1024 / 4 / 256), dim3(256), 0, stream>>>(X, Xb, MROWS * 1024);
  transpose_cast<<<dim3(32, 32, 4), dim3(256), 0, stream>>>(Wq, Wk, Wv, Wo, WqkvT, WoT);

  // 2) fused QKV projection (Q pre-scaled by 1/8), 128x128 tiles
  gemm_bt<128, true, true><<<dim3(MROWS / 128, QKVN / 128), dim3(256), 0, stream>>>(
      Xb, WqkvT, QKV, MROWS, QKVN, EMB);

  // 3) V pre-transpose, then causal flash attention (LDS-shared K/V)
  v_transpose<<<dim3(SEQ / 64, BATCH * HEADS), dim3(256), 0, stream>>>(QKV, Vt);
  attn_fwd<<<dim3(512), dim3(256), 0, stream>>>(QKV, Vt, Cb);

  // 4) output projection (fp32 out), 64x128 tiles (512 blocks, 2/CU)
  gemm_bt<64, false, false><<<dim3(MROWS / 64, PROJ / 128), dim3(256), 0, stream>>>(
      Cb, WoT, out, MROWS, PROJ, PROJ);
}

// Round 10
// 112.471 us; speedup vs baseline: 1.3879x; 1.0302x over previous
//
#include <hip/hip_runtime.h>
#include <stdint.h>

// Problem constants
#define SEQ   2048
#define EMB   1024
#define PROJ  1024
#define HEADS 16
#define HD    64
#define BATCH 2
#define MROWS (BATCH * SEQ)   // 4096
#define QKVN  3072            // fused QKV output width

typedef __attribute__((ext_vector_type(8))) __bf16 bf16x8;
typedef __attribute__((ext_vector_type(4))) __bf16 bf16x4;
typedef __attribute__((ext_vector_type(4))) float  f32x4;

static __device__ __forceinline__ __bf16 f2b(float f) {
  union { float f; uint32_t u; } a; a.f = f;
  uint32_t r = a.u + 0x7FFFu + ((a.u >> 16) & 1u);
  union { uint16_t u; __bf16 b; } o; o.u = (uint16_t)(r >> 16);
  return o.b;
}

#define GLOAD_LDS16(gsrc, ldst)                                                \
  __builtin_amdgcn_global_load_lds(                                            \
      (const __attribute__((address_space(1))) void*)(gsrc),                   \
      (__attribute__((address_space(3))) void*)(ldst), 16, 0, 0)

// ---------------------------------------------------------------------------
// fp32 -> bf16 elementwise cast (vectorized 4/thread)
// ---------------------------------------------------------------------------
__global__ void cast_f32_bf16(const float* __restrict__ in,
                              __bf16* __restrict__ out, int n) {
  int i = (blockIdx.x * blockDim.x + threadIdx.x) * 4;
  if (i + 3 < n) {
    float4 v = *reinterpret_cast<const float4*>(in + i);
    bf16x4 o;
    o[0] = f2b(v.x); o[1] = f2b(v.y); o[2] = f2b(v.z); o[3] = f2b(v.w);
    *reinterpret_cast<bf16x4*>(out + i) = o;
  }
}

// ---------------------------------------------------------------------------
// Transpose + cast the 4 weight matrices. z=0..2 -> rows z*1024.. of WqkvT,
// z=3 -> WoT. T[n][k] = (bf16) W[k][n].
// ---------------------------------------------------------------------------
__global__ void transpose_cast(const float* __restrict__ W0, const float* __restrict__ W1,
                               const float* __restrict__ W2, const float* __restrict__ W3,
                               __bf16* __restrict__ Tqkv, __bf16* __restrict__ To) {
  const float* W; __bf16* T;
  switch (blockIdx.z) {
    case 0: W = W0; T = Tqkv;                       break;
    case 1: W = W1; T = Tqkv + (size_t)1024 * 1024; break;
    case 2: W = W2; T = Tqkv + (size_t)2048 * 1024; break;
    default: W = W3; T = To;                        break;
  }
  __shared__ float tile[32][33];
  int k0 = blockIdx.x * 32, n0 = blockIdx.y * 32;
  int tx = threadIdx.x & 31, ty = threadIdx.x >> 5;  // 256 thr: ty 0..7
#pragma unroll
  for (int r = ty; r < 32; r += 8)
    tile[r][tx] = W[(size_t)(k0 + r) * 1024 + n0 + tx];
  __syncthreads();
#pragma unroll
  for (int r = ty; r < 32; r += 8)
    T[(size_t)(n0 + r) * 1024 + k0 + tx] = f2b(tile[tx][r]);
}

// ---------------------------------------------------------------------------
// bf16 GEMM, C = A[M,K] * Bt^T (Bt[N][K]). Tile BM x 128, BK=32.
// 256 thr = 4 waves in 2x2; wave tile (BM/2) x 64. MFMA 16x16x32.
// SCALE_Q: multiply output by 0.125 when col < 1024 (attention Q pre-scale).
// VSPLIT: cols >= 2048 (the V projection) are written TRANSPOSED into
// vt[(b*16+h)*64+d][s] (bf16x4 per lane; rows of a 128-tile stay within one
// batch since 2048 % 128 == 0) -- replaces the separate v_transpose kernel.
// ---------------------------------------------------------------------------
template <int BM, bool OUT_BF16, bool SCALE_Q, bool VSPLIT>
__global__ __launch_bounds__(256) void gemm_bt(const __bf16* __restrict__ A,
                                               const __bf16* __restrict__ Bt,
                                               void* __restrict__ Cout,
                                               __bf16* __restrict__ vt,
                                               int M, int N, int K) {
  constexpr int MI = BM / 32;  // m-frags per wave
  __shared__ __align__(16) __bf16 As[BM * 32];
  __shared__ __align__(16) __bf16 Bs[128 * 32];
  const int t = threadIdx.x;
  const int lane = t & 63, w = t >> 6;
  const int g = lane >> 4, l15 = lane & 15;
  const int m0 = blockIdx.x * BM, n0 = blockIdx.y * 128;
  const int wr = w >> 1, wc = w & 1;

  f32x4 acc[MI][4];
#pragma unroll
  for (int i = 0; i < MI; i++)
#pragma unroll
    for (int j = 0; j < 4; j++) acc[i][j] = {0.f, 0.f, 0.f, 0.f};

  for (int k0 = 0; k0 < K; k0 += 32) {
    __syncthreads();
#pragma unroll
    for (int c = t; c < BM * 4; c += 256)  // A tile [BM][32]
      GLOAD_LDS16(A + (size_t)(m0 + (c >> 2)) * K + k0 + (c & 3) * 8, As + c * 8);
#pragma unroll
    for (int c = t; c < 512; c += 256)     // Bt tile [128][32]
      GLOAD_LDS16(Bt + (size_t)(n0 + (c >> 2)) * K + k0 + (c & 3) * 8, Bs + c * 8);
    __syncthreads();

    bf16x8 af[MI], bfr[4];
#pragma unroll
    for (int mi = 0; mi < MI; mi++)
      af[mi] = *reinterpret_cast<const bf16x8*>(As + (wr * (BM / 2) + mi * 16 + l15) * 32 + g * 8);
#pragma unroll
    for (int ni = 0; ni < 4; ni++)
      bfr[ni] = *reinterpret_cast<const bf16x8*>(Bs + (wc * 64 + ni * 16 + l15) * 32 + g * 8);
#pragma unroll
    for (int mi = 0; mi < MI; mi++)
#pragma unroll
      for (int ni = 0; ni < 4; ni++)
        acc[mi][ni] = __builtin_amdgcn_mfma_f32_16x16x32_bf16(af[mi], bfr[ni], acc[mi][ni], 0, 0, 0);
  }

#pragma unroll
  for (int mi = 0; mi < MI; mi++)
#pragma unroll
    for (int ni = 0; ni < 4; ni++) {
      int row = m0 + wr * (BM / 2) + mi * 16 + g * 4;
      int col = n0 + wc * 64 + ni * 16 + l15;
      if (VSPLIT && col >= 2048) {  // V projection -> transposed store
        int hd = col - 2048;
        int bb = row >> 11, ss = row & 2047;
        bf16x4 v4;
#pragma unroll
        for (int r = 0; r < 4; r++) v4[r] = f2b(acc[mi][ni][r]);
        *reinterpret_cast<bf16x4*>(vt + ((size_t)((bb * 16 + (hd >> 6)) * 64 + (hd & 63))) * 2048 + ss) = v4;
      } else {
#pragma unroll
        for (int r = 0; r < 4; r++) {
          float v = acc[mi][ni][r];
          if (SCALE_Q && col < 1024) v *= 0.125f;
          if (OUT_BF16)
            ((__bf16*)Cout)[(size_t)(row + r) * N + col] = f2b(v);
          else
            ((float*)Cout)[(size_t)(row + r) * N + col] = v;
        }
      }
    }
}

// ---------------------------------------------------------------------------
// Causal flash attention, LDS-shared K/V, KVBLK=128, pair-balanced blocks.
// Grid 512 blocks x 256 thr (4 waves) = 2 blocks/CU, 8 waves/CU.
// id&7 = xcd (owns 4 heads); bh = (id&7)*4 + ((id>>3)&3); pair = id>>5 (0..15).
// Block runs two 64-row members sequentially: mi = pair, then 31-pair.
// Member mi: virtual 64-kv blocks vv = 0..mi; staged as (mi+2)>>1 128-wide
// tiles (two compute halves per stage) -> barriers per block 33 -> 17.
// Block total tile-iters = (pair+2)/2 + (33-pair)/2 = 17, uniform.
// Wave w owns 16 rows qw = 64*mi + 16*w to completion; causal+pad mask only
// at vv == mi. K[128][64] + V^T[64][128] double-buffered in LDS (reg-staged,
// XOR-swizzle chunk^=(row&7): 2 lanes/bank = free; loads issued BEFORE
// compute, ds_writes after = T14 split). Swapped QK^T (D[kv][q], lane-local
// softmax, M=1), Q pre-scaled by 1/8 in the GEMM.
// launch_bounds min-waves stays 2 (r5 lesson: forcing 4 -> VGPR 64 -> spill).
// ---------------------------------------------------------------------------
__global__ __launch_bounds__(256, 2) void attn_fwd(const __bf16* __restrict__ QKV,
                                                   const __bf16* __restrict__ Vt,
                                                   __bf16* __restrict__ ctx) {
  const int id = blockIdx.x;
  const int bh = (id & 7) * 4 + ((id >> 3) & 3);
  const int pair = id >> 5;                     // 0..15
  const int b = bh >> 4, h = bh & 15;
  const int tid = threadIdx.x, lane = tid & 63, w = tid >> 6;
  const int g = lane >> 4, l15 = lane & 15;

  __shared__ __align__(16) __bf16 Ks[2][128 * 64];   // [kv][d], swizzled
  __shared__ __align__(16) __bf16 Vs[2][64 * 128];   // [d][kv], swizzled
  __shared__ __align__(16) __bf16 P_lds[4][16][72];

  const __bf16* Qg  = QKV + (size_t)b * SEQ * QKVN + h * 64;
  const __bf16* Kg  = Qg + 1024;
  const __bf16* VtH = Vt + (size_t)bh * 64 * 2048;
  __bf16* Cg = ctx + (size_t)b * SEQ * 1024 + h * 64;

  // staging geometry: 1024 K-chunks (16B) + 1024 V-chunks per 128-kv tile;
  // thread handles 4 of each. K chunk c: row=c>>3 (kv 0..127), j=c&7.
  // V chunk c: row=c>>4 (d 0..63), j=c&15. Swizzle: chunk' = j ^ (row&7).
  const int xw = l15 & 7;  // read-side row XOR (rows == l15 mod 8)

  for (int mem = 0; mem < 2; ++mem) {
    const int mi = mem ? (31 - pair) : pair;    // 0..31, 64-row members
    const int qw = mi * 64 + 16 * w;            // wave's 16 rows
    const int qi = qw + l15;
    const int Tt = (mi + 2) >> 1;               // 128-wide tiles

    // Q fragments: qf[ks][j] = Q[qw+l15][ks*32+g*8+j]
    bf16x8 qf[2];
#pragma unroll
    for (int ks = 0; ks < 2; ks++)
      qf[ks] = *reinterpret_cast<const bf16x8*>(
          Qg + (size_t)(qw + l15) * QKVN + ks * 32 + g * 8);

    f32x4 acco[4];
    float mrun = -1e30f, lrun = 0.f;
#pragma unroll
    for (int nd = 0; nd < 4; nd++) acco[nd] = {0.f, 0.f, 0.f, 0.f};

    // prologue: stage tile 0 into buffer 0
    {
#pragma unroll
      for (int k = 0; k < 4; k++) {
        const int c = tid + 256 * k;
        const int rk = c >> 3, jk = c & 7;
        const int rv = c >> 4, jv = c & 15;
        bf16x8 kv = *reinterpret_cast<const bf16x8*>(Kg + (size_t)rk * QKVN + jk * 8);
        bf16x8 vv = *reinterpret_cast<const bf16x8*>(VtH + (size_t)rv * 2048 + jv * 8);
        *reinterpret_cast<bf16x8*>(Ks[0] + rk * 64 + ((jk ^ (rk & 7)) * 8)) = kv;
        *reinterpret_cast<bf16x8*>(Vs[0] + rv * 128 + ((jv ^ (rv & 7)) * 8)) = vv;
      }
    }
    __syncthreads();

    for (int it = 0; it < Tt; ++it) {
      const int cur = it & 1, nxt = cur ^ 1;
      const bool hn = (it + 1 < Tt);
      bf16x8 skv[4], svv[4];
      if (hn) {  // issue next tile's global loads early (T14 split)
        const size_t kvn = (size_t)(it + 1) * 128;
#pragma unroll
        for (int k = 0; k < 4; k++) {
          const int c = tid + 256 * k;
          const int rk = c >> 3, jk = c & 7;
          const int rv = c >> 4, jv = c & 15;
          skv[k] = *reinterpret_cast<const bf16x8*>(Kg + (kvn + rk) * QKVN + jk * 8);
          svv[k] = *reinterpret_cast<const bf16x8*>(VtH + (size_t)rv * 2048 + kvn + jv * 8);
        }
      }

      const __bf16* Kc = Ks[cur];
      const __bf16* Vc = Vs[cur];
#pragma unroll
      for (int hf = 0; hf < 2; hf++) {   // two 64-kv compute halves per stage
        const int vv = it * 2 + hf;
        if (vv <= mi) {
          const int kv0 = vv * 64;
          const bool maskme = (vv == mi);

          // ---- QK^T (swapped): accS[nb], D[kv][q], q = qw+l15
          f32x4 accS[4];
#pragma unroll
          for (int nb = 0; nb < 4; nb++) accS[nb] = {0.f, 0.f, 0.f, 0.f};
#pragma unroll
          for (int nb = 0; nb < 4; nb++) {
            const int row = (hf * 64 + nb * 16 + l15) * 64;
            bf16x8 kf0 = *reinterpret_cast<const bf16x8*>(Kc + row + ((g ^ xw) * 8));
            bf16x8 kf1 = *reinterpret_cast<const bf16x8*>(Kc + row + (((4 + g) ^ xw) * 8));
            accS[nb] = __builtin_amdgcn_mfma_f32_16x16x32_bf16(kf0, qf[0], accS[nb], 0, 0, 0);
            accS[nb] = __builtin_amdgcn_mfma_f32_16x16x32_bf16(kf1, qf[1], accS[nb], 0, 0, 0);
          }

          // ---- causal + pad mask (last virtual block only)
          if (maskme) {
#pragma unroll
            for (int nb = 0; nb < 4; nb++)
#pragma unroll
              for (int r = 0; r < 4; r++) {
                int kvi = kv0 + nb * 16 + g * 4 + r;
                if (kvi > qi) accS[nb][r] = -1e30f;
              }
          }

          // ---- online softmax (row = lane's own q), defer-max THR=8
          {
            float pmax = -1e30f;
#pragma unroll
            for (int nb = 0; nb < 4; nb++)
#pragma unroll
              for (int r = 0; r < 4; r++) pmax = fmaxf(pmax, accS[nb][r]);
            pmax = fmaxf(pmax, __shfl_xor(pmax, 16));
            pmax = fmaxf(pmax, __shfl_xor(pmax, 32));
            if (!__all(pmax <= mrun + 8.0f)) {
              float mnew = fmaxf(mrun, pmax);
              float corr = __expf(mrun - mnew);
              mrun = mnew;
              lrun *= corr;
#pragma unroll
              for (int r = 0; r < 4; r++) {
                float cr = __shfl(corr, (g << 4) + (g << 2) + r);
#pragma unroll
                for (int nd = 0; nd < 4; nd++) acco[nd][r] *= cr;
              }
            }
            float lsum = 0.f;
#pragma unroll
            for (int nb = 0; nb < 4; nb++) {
              bf16x4 pk;
#pragma unroll
              for (int r = 0; r < 4; r++) {
                float pv = __expf(accS[nb][r] - mrun);
                lsum += pv;
                pk[r] = (__bf16)pv;
              }
              *reinterpret_cast<bf16x4*>(&P_lds[w][l15][nb * 16 + g * 4]) = pk;
            }
            lsum += __shfl_xor(lsum, 16);
            lsum += __shfl_xor(lsum, 32);
            lrun += lsum;
          }

          // ---- PV: O[q][d] += P[q][kv] * V[kv][d]
          {
            bf16x8 pa0 = *reinterpret_cast<const bf16x8*>(&P_lds[w][l15][g * 8]);
            bf16x8 pa1 = *reinterpret_cast<const bf16x8*>(&P_lds[w][l15][32 + g * 8]);
#pragma unroll
            for (int nd = 0; nd < 4; nd++) {
              const int row = (nd * 16 + l15) * 128;
              bf16x8 vb0 = *reinterpret_cast<const bf16x8*>(Vc + row + (((hf * 8 + g) ^ xw) * 8));
              bf16x8 vb1 = *reinterpret_cast<const bf16x8*>(Vc + row + (((hf * 8 + 4 + g) ^ xw) * 8));
              acco[nd] = __builtin_amdgcn_mfma_f32_16x16x32_bf16(pa0, vb0, acco[nd], 0, 0, 0);
              acco[nd] = __builtin_amdgcn_mfma_f32_16x16x32_bf16(pa1, vb1, acco[nd], 0, 0, 0);
            }
          }
        }
      }

      if (hn) {  // write staged regs to the other buffer
#pragma unroll
        for (int k = 0; k < 4; k++) {
          const int c = tid + 256 * k;
          const int rk = c >> 3, jk = c & 7;
          const int rv = c >> 4, jv = c & 15;
          *reinterpret_cast<bf16x8*>(Ks[nxt] + rk * 64 + ((jk ^ (rk & 7)) * 8)) = skv[k];
          *reinterpret_cast<bf16x8*>(Vs[nxt] + rv * 128 + ((jv ^ (rv & 7)) * 8)) = svv[k];
        }
      }
      __syncthreads();
    }

    // epilogue: ctx = O / l for this wave's 16 rows
    {
      float inv = 1.0f / lrun;
#pragma unroll
      for (int r = 0; r < 4; r++) {
        float ir = __shfl(inv, (g << 4) + (g << 2) + r);
        int qrow = qw + g * 4 + r;
#pragma unroll
        for (int nd = 0; nd < 4; nd++)
          Cg[(size_t)qrow * 1024 + nd * 16 + l15] = (__bf16)(acco[nd][r] * ir);
      }
    }
  }
}

// ---------------------------------------------------------------------------
extern "C" void kernel_launch(void* const* d_in, const int* in_sizes, int n_in,
                              void* d_out, int out_size, void* d_ws, size_t ws_size,
                              hipStream_t stream) {
  const float* X  = (const float*)d_in[0];
  const float* Wq = (const float*)d_in[1];
  const float* Wk = (const float*)d_in[2];
  const float* Wv = (const float*)d_in[3];
  const float* Wo = (const float*)d_in[4];
  float* out = (float*)d_out;

  uint8_t* ws = (uint8_t*)d_ws;
  size_t off = 0;
  const size_t actBytes = (size_t)MROWS * 1024 * 2;          // 8 MB
  __bf16* Xb    = (__bf16*)(ws + off); off += actBytes;      // freed after QKV gemm
  __bf16* WqkvT = (__bf16*)(ws + off); off += (size_t)QKVN * 1024 * 2;
  __bf16* WoT   = (__bf16*)(ws + off); off += (size_t)1024 * 1024 * 2;
  __bf16* QKV   = (__bf16*)(ws + off); off += (size_t)MROWS * QKVN * 2;
  __bf16* Vt    = (__bf16*)(ws + off); off += actBytes;
  __bf16* Cb    = Xb;  // alias: X dead after QKV projection

  // 1) casts
  cast_f32_bf16<<<dim3(MROWS * 1024 / 4 / 256), dim3(256), 0, stream>>>(X, Xb, MROWS * 1024);
  transpose_cast<<<dim3(32, 32, 4), dim3(256), 0, stream>>>(Wq, Wk, Wv, Wo, WqkvT, WoT);

  // 2) fused QKV projection (Q pre-scaled by 1/8; V written transposed to Vt)
  gemm_bt<128, true, true, true><<<dim3(MROWS / 128, QKVN / 128), dim3(256), 0, stream>>>(
      Xb, WqkvT, QKV, Vt, MROWS, QKVN, EMB);

  // 3) causal flash attention (LDS-shared K/V, KVBLK=128)
  attn_fwd<<<dim3(512), dim3(256), 0, stream>>>(QKV, Vt, Cb);

  // 4) output projection (fp32 out), 64x128 tiles (512 blocks, 2/CU)
  gemm_bt<64, false, false, false><<<dim3(MROWS / 64, PROJ / 128), dim3(256), 0, stream>>>(
      Cb, WoT, out, nullptr, MROWS, PROJ, PROJ);
}